// Round 8
// baseline (2150.644 us; speedup 1.0000x reference)
//
#include <hip/hip_runtime.h>
#include <math.h>

#define NT 512

// ---- LDS (doubles only; no weights in LDS) ----
#define D_YBUF 0
#define D_YCUR 64
#define D_KACC 128
#define D_H1   192    // 128
#define D_D1   320    // 128
#define D_H2   448    // 128
#define D_D2   576    // 128
#define D_FB   704    // 512
#define D_T3   1216   // 512
#define D_WM   1728   // 8*66
#define D_U1   2256   // 8*130
#define D_U2   3296   // 8*130
#define D_VSIG 4336   // 16*36
#define D_CMAT 4912   // 64
#define D_HID  4976   // 17*64
#define D_X0   6064   // 8
#define D_H2IC 6072   // 128 (ic only)
#define D_TOTAL 6200

static __device__ __forceinline__ double lipswish_d(double z, double* d) {
    double s = 1.0 / (1.0 + exp(-z));
    *d = 0.909 * s * (1.0 + z * (1.0 - s));
    return 0.909 * z * s;
}

static __device__ __forceinline__ double red_xor(double s, int m) {
    return __shfl_xor(s, m, 64);
}

extern "C" __global__ void __launch_bounds__(NT, 1)
ncde_solve(const float* __restrict__ x,
           const float* __restrict__ ic_w1, const float* __restrict__ ic_b1,
           const float* __restrict__ ic_w2, const float* __restrict__ ic_b2,
           const float* __restrict__ ic_w3, const float* __restrict__ ic_b3,
           const float* __restrict__ vf_w1, const float* __restrict__ vf_b1,
           const float* __restrict__ vf_w2, const float* __restrict__ vf_b2,
           const float* __restrict__ vf_w3, const float* __restrict__ vf_b3,
           const float* __restrict__ ro_w,  const float* __restrict__ ro_b,
           float* __restrict__ out)
{
    __shared__ double smd[D_TOTAL];

    const int t = threadIdx.x;
    const int b = blockIdx.x;
    const float* xb = x + (size_t)b * (257 * 8);

    const int rp1 = t >> 3, p1 = t & 7;    // W1: rows 2rp1..+2, cols 8p1..+8
    const int rq2 = t >> 3, p2 = t & 7;    // W2: rows 2rq2..+2, cols 16p2..+16
    const int rq3 = t >> 2, q  = t & 3;    // W3: rows 4rq3..+4, cols 32q..+32
    const int wv  = t >> 6;                // tangent index for WM/T3

    // ---- weights in registers ----
    double w1d[2][8];
    #pragma unroll
    for (int r = 0; r < 2; ++r) {
        const float4* src = reinterpret_cast<const float4*>(vf_w1 + (2 * rp1 + r) * 64 + 8 * p1);
        float4 v0 = src[0], v1 = src[1];
        w1d[r][0] = (double)v0.x; w1d[r][1] = (double)v0.y;
        w1d[r][2] = (double)v0.z; w1d[r][3] = (double)v0.w;
        w1d[r][4] = (double)v1.x; w1d[r][5] = (double)v1.y;
        w1d[r][6] = (double)v1.z; w1d[r][7] = (double)v1.w;
    }
    double w2d[2][16];
    #pragma unroll
    for (int r = 0; r < 2; ++r) {
        const float4* src = reinterpret_cast<const float4*>(vf_w2 + (2 * rq2 + r) * 128 + 16 * p2);
        #pragma unroll
        for (int jj = 0; jj < 4; ++jj) {
            float4 v = src[jj];
            w2d[r][4 * jj]     = (double)v.x;
            w2d[r][4 * jj + 1] = (double)v.y;
            w2d[r][4 * jj + 2] = (double)v.z;
            w2d[r][4 * jj + 3] = (double)v.w;
        }
    }
    float w3f[4][32];
    #pragma unroll
    for (int r = 0; r < 4; ++r) {
        const float4* src = reinterpret_cast<const float4*>(vf_w3 + (size_t)(4 * rq3 + r) * 128 + 32 * q);
        #pragma unroll
        for (int jj = 0; jj < 8; ++jj) {
            float4 v = src[jj];
            w3f[r][4 * jj]     = v.x;
            w3f[r][4 * jj + 1] = v.y;
            w3f[r][4 * jj + 2] = v.z;
            w3f[r][4 * jj + 3] = v.w;
        }
    }
    const double b1p0 = (double)vf_b1[2 * rp1], b1p1 = (double)vf_b1[2 * rp1 + 1];
    const double b2p0 = (double)vf_b2[2 * rq2], b2p1 = (double)vf_b2[2 * rq2 + 1];
    double b3p[4];
    #pragma unroll
    for (int r = 0; r < 4; ++r) b3p[r] = (double)vf_b3[4 * rq3 + r];

    // ==== init: X0 + logsigs ====
    if (t < 8) smd[D_X0 + t] = (double)xb[t];
    if (t < 16) {
        const float* xr = xb + t * 16 * 8;
        double cum[8], area[28], prev[8];
        #pragma unroll
        for (int i = 0; i < 8; ++i) { cum[i] = 0.0; prev[i] = (double)xr[i]; }
        #pragma unroll
        for (int u = 0; u < 28; ++u) area[u] = 0.0;
        for (int k = 1; k <= 16; ++k) {
            double dx[8];
            #pragma unroll
            for (int i = 0; i < 8; ++i) {
                double c = (double)xr[k * 8 + i];
                dx[i] = c - prev[i];
                prev[i] = c;
            }
            #pragma unroll
            for (int i = 0; i < 7; ++i) {
                #pragma unroll
                for (int j = i + 1; j < 8; ++j) {
                    int u = 7 * i - (i * (i - 1)) / 2 + (j - i - 1);
                    area[u] += 0.5 * (cum[i] * dx[j] - cum[j] * dx[i]);
                }
            }
            #pragma unroll
            for (int i = 0; i < 8; ++i) cum[i] += dx[i];
        }
        #pragma unroll
        for (int i = 0; i < 8; ++i) smd[D_VSIG + t * 36 + i] = cum[i];
        #pragma unroll
        for (int u = 0; u < 28; ++u) smd[D_VSIG + t * 36 + 8 + u] = area[u];
    }
    __syncthreads();

    // ==== ic MLP (one-time, weights from global) ====
    if (t < 128) {
        double acc = (double)ic_b1[t];
        #pragma unroll
        for (int e = 0; e < 8; ++e) acc += (double)ic_w1[t * 8 + e] * smd[D_X0 + e];
        double d;
        smd[D_H1 + t] = lipswish_d(acc, &d);
    }
    __syncthreads();
    if (t < 128) {
        const float4* wr = reinterpret_cast<const float4*>(ic_w2 + t * 128);
        double a0 = 0.0, a1 = 0.0, a2 = 0.0, a3 = 0.0;
        #pragma unroll
        for (int k = 0; k < 32; ++k) {
            float4 wvv = wr[k];
            double2 h0 = *reinterpret_cast<const double2*>(&smd[D_H1 + 4 * k]);
            double2 h1 = *reinterpret_cast<const double2*>(&smd[D_H1 + 4 * k + 2]);
            a0 += (double)wvv.x * h0.x; a1 += (double)wvv.y * h0.y;
            a2 += (double)wvv.z * h1.x; a3 += (double)wvv.w * h1.y;
        }
        double d;
        smd[D_H2IC + t] = lipswish_d((double)ic_b2[t] + (a0 + a2) + (a1 + a3), &d);
    }
    __syncthreads();
    if (t < 64) {
        const float4* wr = reinterpret_cast<const float4*>(ic_w3 + t * 128);
        double a0 = 0.0, a1 = 0.0, a2 = 0.0, a3 = 0.0;
        #pragma unroll
        for (int k = 0; k < 32; ++k) {
            float4 wvv = wr[k];
            double2 h0 = *reinterpret_cast<const double2*>(&smd[D_H2IC + 4 * k]);
            double2 h1 = *reinterpret_cast<const double2*>(&smd[D_H2IC + 4 * k + 2]);
            a0 += (double)wvv.x * h0.x; a1 += (double)wvv.y * h0.y;
            a2 += (double)wvv.z * h1.x; a3 += (double)wvv.w * h1.y;
        }
        double y0 = (double)ic_b3[t] + (a0 + a2) + (a1 + a3);
        smd[D_YCUR + t] = y0;
        smd[D_YBUF + t] = y0;
        smd[D_HID + t]  = y0;
        int a = t >> 3, bb = t & 7;
        double cv = 0.0;
        if (a != bb) {
            int i = a < bb ? a : bb;
            int j = a < bb ? bb : a;
            int pidx = 7 * i - (i * (i - 1)) / 2 + (j - i - 1);
            double vv = smd[D_VSIG + 8 + pidx];
            cv = (a > bb) ? vv : -vv;
        }
        smd[D_CMAT + t] = cv;
    }
    __syncthreads();

    // ==== RK4 scan ====
    for (int w = 0; w < 16; ++w) {
        for (int stage = 0; stage < 4; ++stage) {
            // ---- A: L1 (reg weights, butterfly over p1) ----
            {
                double a0 = 0.0, a1 = 0.0;
                #pragma unroll
                for (int j = 0; j < 8; j += 2) {
                    double2 yv = *reinterpret_cast<const double2*>(&smd[D_YBUF + 8 * p1 + j]);
                    a0 += w1d[0][j] * yv.x + w1d[0][j + 1] * yv.y;
                    a1 += w1d[1][j] * yv.x + w1d[1][j + 1] * yv.y;
                }
                a0 += red_xor(a0, 1); a1 += red_xor(a1, 1);
                a0 += red_xor(a0, 2); a1 += red_xor(a1, 2);
                a0 += red_xor(a0, 4); a1 += red_xor(a1, 4);
                if (p1 == 0) {
                    double d0, d1;
                    double h0 = lipswish_d(a0 + b1p0, &d0);
                    double h1 = lipswish_d(a1 + b1p1, &d1);
                    double2 hv; hv.x = h0; hv.y = h1;
                    double2 dv; dv.x = d0; dv.y = d1;
                    *reinterpret_cast<double2*>(&smd[D_H1 + 2 * rp1]) = hv;
                    *reinterpret_cast<double2*>(&smd[D_D1 + 2 * rp1]) = dv;
                }
            }
            __syncthreads();
            // ---- B: L2 ----
            {
                double a0 = 0.0, a1 = 0.0;
                #pragma unroll
                for (int j = 0; j < 16; j += 2) {
                    double2 hv = *reinterpret_cast<const double2*>(&smd[D_H1 + 16 * p2 + j]);
                    a0 += w2d[0][j] * hv.x + w2d[0][j + 1] * hv.y;
                    a1 += w2d[1][j] * hv.x + w2d[1][j + 1] * hv.y;
                }
                a0 += red_xor(a0, 1); a1 += red_xor(a1, 1);
                a0 += red_xor(a0, 2); a1 += red_xor(a1, 2);
                a0 += red_xor(a0, 4); a1 += red_xor(a1, 4);
                if (p2 == 0) {
                    double d0, d1;
                    double h0 = lipswish_d(a0 + b2p0, &d0);
                    double h1 = lipswish_d(a1 + b2p1, &d1);
                    double2 hv; hv.x = h0; hv.y = h1;
                    double2 dv; dv.x = d0; dv.y = d1;
                    *reinterpret_cast<double2*>(&smd[D_H2 + 2 * rq2]) = hv;
                    *reinterpret_cast<double2*>(&smd[D_D2 + 2 * rq2]) = dv;
                }
            }
            __syncthreads();
            // ---- C: L3, F kept in regs at q==0 ----
            double Freg[4];
            {
                double ac[4] = {0.0, 0.0, 0.0, 0.0};
                #pragma unroll
                for (int j = 0; j < 32; j += 2) {
                    double2 hv = *reinterpret_cast<const double2*>(&smd[D_H2 + 32 * q + j]);
                    #pragma unroll
                    for (int r = 0; r < 4; ++r)
                        ac[r] += (double)w3f[r][j] * hv.x + (double)w3f[r][j + 1] * hv.y;
                }
                #pragma unroll
                for (int r = 0; r < 4; ++r) {
                    ac[r] += red_xor(ac[r], 1);
                    ac[r] += red_xor(ac[r], 2);
                }
                if (q == 0) {
                    #pragma unroll
                    for (int r = 0; r < 4; ++r) Freg[r] = tanh(ac[r] + b3p[r]);
                    double2 f0; f0.x = Freg[0]; f0.y = Freg[1];
                    double2 f1; f1.x = Freg[2]; f1.y = Freg[3];
                    *reinterpret_cast<double2*>(&smd[D_FB + 4 * rq3])     = f0;
                    *reinterpret_cast<double2*>(&smd[D_FB + 4 * rq3 + 2]) = f1;
                }
            }
            __syncthreads();
            // ---- WM: wm[a][e] ----
            {
                int e = t & 63;
                double s = 0.0;
                #pragma unroll
                for (int bb = 0; bb < 8; ++bb)
                    s += smd[D_CMAT + wv * 8 + bb] * smd[D_FB + bb * 64 + e];
                smd[D_WM + wv * 66 + e] = s;
            }
            __syncthreads();
            // ---- U1: batched over a, reg W1 ----
            {
                double2 d1v = *reinterpret_cast<const double2*>(&smd[D_D1 + 2 * rp1]);
                for (int a = 0; a < 8; ++a) {
                    double a0 = 0.0, a1 = 0.0;
                    #pragma unroll
                    for (int j = 0; j < 8; j += 2) {
                        double2 mv = *reinterpret_cast<const double2*>(&smd[D_WM + a * 66 + 8 * p1 + j]);
                        a0 += w1d[0][j] * mv.x + w1d[0][j + 1] * mv.y;
                        a1 += w1d[1][j] * mv.x + w1d[1][j + 1] * mv.y;
                    }
                    a0 += red_xor(a0, 1); a1 += red_xor(a1, 1);
                    a0 += red_xor(a0, 2); a1 += red_xor(a1, 2);
                    a0 += red_xor(a0, 4); a1 += red_xor(a1, 4);
                    if (p1 == 0) {
                        double2 uv; uv.x = a0 * d1v.x; uv.y = a1 * d1v.y;
                        *reinterpret_cast<double2*>(&smd[D_U1 + a * 130 + 2 * rp1]) = uv;
                    }
                }
            }
            __syncthreads();
            // ---- U2: batched over a, reg W2 ----
            {
                double2 d2v = *reinterpret_cast<const double2*>(&smd[D_D2 + 2 * rq2]);
                for (int a = 0; a < 8; ++a) {
                    double a0 = 0.0, a1 = 0.0;
                    #pragma unroll
                    for (int j = 0; j < 16; j += 2) {
                        double2 uv = *reinterpret_cast<const double2*>(&smd[D_U1 + a * 130 + 16 * p2 + j]);
                        a0 += w2d[0][j] * uv.x + w2d[0][j + 1] * uv.y;
                        a1 += w2d[1][j] * uv.x + w2d[1][j + 1] * uv.y;
                    }
                    a0 += red_xor(a0, 1); a1 += red_xor(a1, 1);
                    a0 += red_xor(a0, 2); a1 += red_xor(a1, 2);
                    a0 += red_xor(a0, 4); a1 += red_xor(a1, 4);
                    if (p2 == 0) {
                        double2 ov; ov.x = a0 * d2v.x; ov.y = a1 * d2v.y;
                        *reinterpret_cast<double2*>(&smd[D_U2 + a * 130 + 2 * rq2]) = ov;
                    }
                }
            }
            __syncthreads();
            // ---- T3: reg W3, tangent wv; fold v[a]*F ----
            {
                double ac[4] = {0.0, 0.0, 0.0, 0.0};
                #pragma unroll
                for (int j = 0; j < 32; j += 2) {
                    double2 uv = *reinterpret_cast<const double2*>(&smd[D_U2 + wv * 130 + 32 * q + j]);
                    #pragma unroll
                    for (int r = 0; r < 4; ++r)
                        ac[r] += (double)w3f[r][j] * uv.x + (double)w3f[r][j + 1] * uv.y;
                }
                #pragma unroll
                for (int r = 0; r < 4; ++r) {
                    ac[r] += red_xor(ac[r], 1);
                    ac[r] += red_xor(ac[r], 2);
                }
                if (q == 0) {
                    double va = smd[D_VSIG + w * 36 + wv];
                    double t3v[4];
                    #pragma unroll
                    for (int r = 0; r < 4; ++r)
                        t3v[r] = va * Freg[r] + (1.0 - Freg[r] * Freg[r]) * ac[r];
                    double2 o0; o0.x = t3v[0]; o0.y = t3v[1];
                    double2 o1; o1.x = t3v[2]; o1.y = t3v[3];
                    *reinterpret_cast<double2*>(&smd[D_T3 + 4 * rq3])     = o0;
                    *reinterpret_cast<double2*>(&smd[D_T3 + 4 * rq3 + 2]) = o1;
                }
            }
            __syncthreads();
            // ---- E: combine + RK4 glue (+ next CMAT at stage 3) ----
            if (t < 64) {
                double g = 0.0;
                #pragma unroll
                for (int a = 0; a < 8; ++a) g += smd[D_T3 + a * 64 + t];
                double y = smd[D_YCUR + t];
                if (stage == 0)      { smd[D_KACC + t] = g;        smd[D_YBUF + t] = y + 0.5 * g; }
                else if (stage == 1) { smd[D_KACC + t] += 2.0 * g; smd[D_YBUF + t] = y + 0.5 * g; }
                else if (stage == 2) { smd[D_KACC + t] += 2.0 * g; smd[D_YBUF + t] = y + g; }
                else {
                    double yn = y + (smd[D_KACC + t] + g) * (1.0 / 6.0);
                    smd[D_YCUR + t] = yn;
                    smd[D_YBUF + t] = yn;
                    smd[D_HID + (w + 1) * 64 + t] = yn;
                }
            } else if (t < 128 && stage == 3 && w < 15) {
                int idx = t - 64;
                int a = idx >> 3, bb = idx & 7;
                double cv = 0.0;
                if (a != bb) {
                    int i = a < bb ? a : bb;
                    int j = a < bb ? bb : a;
                    int pidx = 7 * i - (i * (i - 1)) / 2 + (j - i - 1);
                    double vv = smd[D_VSIG + (w + 1) * 36 + 8 + pidx];
                    cv = (a > bb) ? vv : -vv;
                }
                smd[D_CMAT + idx] = cv;
            }
            __syncthreads();
        }
    }

    // ==== readout ====
    for (int idx = t; idx < 544; idx += NT) {
        int s = idx >> 5, oo = idx & 31;
        double acc = (double)ro_b[oo];
        const float* wr = ro_w + oo * 64;
        const double* hr = &smd[D_HID + s * 64];
        #pragma unroll
        for (int d = 0; d < 64; ++d) acc += (double)wr[d] * hr[d];
        out[(size_t)b * 544 + idx] = (float)acc;
    }
}

extern "C" void kernel_launch(void* const* d_in, const int* in_sizes, int n_in,
                              void* d_out, int out_size, void* d_ws, size_t ws_size,
                              hipStream_t stream) {
    const float* x     = (const float*)d_in[0];
    const float* ic_w1 = (const float*)d_in[1];
    const float* ic_b1 = (const float*)d_in[2];
    const float* ic_w2 = (const float*)d_in[3];
    const float* ic_b2 = (const float*)d_in[4];
    const float* ic_w3 = (const float*)d_in[5];
    const float* ic_b3 = (const float*)d_in[6];
    const float* vf_w1 = (const float*)d_in[7];
    const float* vf_b1 = (const float*)d_in[8];
    const float* vf_w2 = (const float*)d_in[9];
    const float* vf_b2 = (const float*)d_in[10];
    const float* vf_w3 = (const float*)d_in[11];
    const float* vf_b3 = (const float*)d_in[12];
    const float* ro_w  = (const float*)d_in[13];
    const float* ro_b  = (const float*)d_in[14];
    float* out = (float*)d_out;

    int B = in_sizes[0] / (257 * 8);
    hipLaunchKernelGGL(ncde_solve, dim3(B), dim3(NT), 0, stream,
                       x, ic_w1, ic_b1, ic_w2, ic_b2, ic_w3, ic_b3,
                       vf_w1, vf_b1, vf_w2, vf_b2, vf_w3, vf_b3, ro_w, ro_b, out);
}

// Round 9
// 2031.340 us; speedup vs baseline: 1.0587x; 1.0587x over previous
//
#include <hip/hip_runtime.h>
#include <math.h>

#define NT 1024

// ---- LDS (doubles), padded layouts ----
// pad8(j)=j+2*(j>>3)  pad16(j)=j+2*(j>>4)
#define D_YBUF 0      // 80  (64 padded by 2/8)
#define D_YCUR 80     // 64
#define D_KACC 144    // 64
#define D_H1   208    // 144 (128 padded 2/16)
#define D_D1   352    // 128
#define D_H2   480    // 144
#define D_D2   624    // 128
#define D_FB   752    // 512 (also ic h1 scratch)
#define D_T3   1264   // 512 (also ic h2 scratch)
#define D_WM   1776   // 8*80
#define D_U1   2416   // 8*144
#define D_U2   3568   // 8*144
#define D_VSIG 4720   // 16*36
#define D_CMAT 5296   // 64
#define D_HID  5360   // 17*64
#define D_X0   6448   // 8
#define D_TOTAL 6456

static __device__ __forceinline__ double lipswish_d(double z, double* d) {
    double s = 1.0 / (1.0 + exp(-z));
    *d = 0.909 * s * (1.0 + z * (1.0 - s));
    return 0.909 * z * s;
}

template<int CTRL>
static __device__ __forceinline__ double dpp_mov_d(double v) {
    long long xx = __double_as_longlong(v);
    int lo = (int)(xx & 0xffffffffLL);
    int hi = (int)(xx >> 32);
    lo = __builtin_amdgcn_update_dpp(0, lo, CTRL, 0xF, 0xF, false);
    hi = __builtin_amdgcn_update_dpp(0, hi, CTRL, 0xF, 0xF, false);
    return __longlong_as_double(((long long)hi << 32) | (unsigned int)lo);
}
// sum within groups of 8 lanes (all lanes get result)
static __device__ __forceinline__ double red8(double v) {
    v += dpp_mov_d<0xB1>(v);    // quad_perm [1,0,3,2]  : xor 1
    v += dpp_mov_d<0x4E>(v);    // quad_perm [2,3,0,1]  : xor 2
    v += dpp_mov_d<0x141>(v);   // row_half_mirror      : xor 4 (within 8)
    return v;
}
// sum within lane pairs
static __device__ __forceinline__ double red2(double v) {
    return v + dpp_mov_d<0xB1>(v);
}

extern "C" __global__ void __launch_bounds__(NT, 1)
ncde_solve(const float* __restrict__ x,
           const float* __restrict__ ic_w1, const float* __restrict__ ic_b1,
           const float* __restrict__ ic_w2, const float* __restrict__ ic_b2,
           const float* __restrict__ ic_w3, const float* __restrict__ ic_b3,
           const float* __restrict__ vf_w1, const float* __restrict__ vf_b1,
           const float* __restrict__ vf_w2, const float* __restrict__ vf_b2,
           const float* __restrict__ vf_w3, const float* __restrict__ vf_b3,
           const float* __restrict__ ro_w,  const float* __restrict__ ro_b,
           float* __restrict__ out)
{
    __shared__ double smd[D_TOTAL];

    const int t = threadIdx.x;
    const int b = blockIdx.x;
    const float* xb = x + (size_t)b * (257 * 8);

    const int o = t >> 3, p = t & 7;        // L1/L2/U1/U2: output row o, K-slice p
    const int row3 = t >> 1, q = t & 1;     // L3/T3: output row row3, K-half q
    const int aT = t >> 7;                  // T3/WM tangent

    // ---- weights in f64 registers ----
    double w1d[8];
    {
        const float4* s4 = reinterpret_cast<const float4*>(vf_w1 + o * 64 + 8 * p);
        float4 v0 = s4[0], v1 = s4[1];
        w1d[0] = v0.x; w1d[1] = v0.y; w1d[2] = v0.z; w1d[3] = v0.w;
        w1d[4] = v1.x; w1d[5] = v1.y; w1d[6] = v1.z; w1d[7] = v1.w;
    }
    double w2d[16];
    {
        const float4* s4 = reinterpret_cast<const float4*>(vf_w2 + o * 128 + 16 * p);
        #pragma unroll
        for (int jj = 0; jj < 4; ++jj) {
            float4 v = s4[jj];
            w2d[4 * jj] = v.x; w2d[4 * jj + 1] = v.y;
            w2d[4 * jj + 2] = v.z; w2d[4 * jj + 3] = v.w;
        }
    }
    double w3d[64];
    {
        const float4* s4 = reinterpret_cast<const float4*>(vf_w3 + (size_t)row3 * 128 + 64 * q);
        #pragma unroll
        for (int jj = 0; jj < 16; ++jj) {
            float4 v = s4[jj];
            w3d[4 * jj] = v.x; w3d[4 * jj + 1] = v.y;
            w3d[4 * jj + 2] = v.z; w3d[4 * jj + 3] = v.w;
        }
    }
    const double b1o = (double)vf_b1[o];
    const double b2o = (double)vf_b2[o];
    const double b3r = (double)vf_b3[row3];

    // ==== init: X0 + logsigs ====
    if (t < 8) smd[D_X0 + t] = (double)xb[t];
    if (t < 16) {
        const float* xr = xb + t * 16 * 8;
        double cum[8], area[28], prev[8];
        #pragma unroll
        for (int i = 0; i < 8; ++i) { cum[i] = 0.0; prev[i] = (double)xr[i]; }
        #pragma unroll
        for (int u = 0; u < 28; ++u) area[u] = 0.0;
        for (int k = 1; k <= 16; ++k) {
            double dx[8];
            #pragma unroll
            for (int i = 0; i < 8; ++i) {
                double c = (double)xr[k * 8 + i];
                dx[i] = c - prev[i];
                prev[i] = c;
            }
            #pragma unroll
            for (int i = 0; i < 7; ++i) {
                #pragma unroll
                for (int j = i + 1; j < 8; ++j) {
                    int u = 7 * i - (i * (i - 1)) / 2 + (j - i - 1);
                    area[u] += 0.5 * (cum[i] * dx[j] - cum[j] * dx[i]);
                }
            }
            #pragma unroll
            for (int i = 0; i < 8; ++i) cum[i] += dx[i];
        }
        #pragma unroll
        for (int i = 0; i < 8; ++i) smd[D_VSIG + t * 36 + i] = cum[i];
        #pragma unroll
        for (int u = 0; u < 28; ++u) smd[D_VSIG + t * 36 + 8 + u] = area[u];
    }
    __syncthreads();

    // ==== ic MLP (scratch: FB=h1ic, T3=h2ic) ====
    if (t < 128) {
        double acc = (double)ic_b1[t];
        #pragma unroll
        for (int e = 0; e < 8; ++e) acc += (double)ic_w1[t * 8 + e] * smd[D_X0 + e];
        double d;
        smd[D_FB + t] = lipswish_d(acc, &d);
    }
    __syncthreads();
    if (t < 128) {
        const float4* wr = reinterpret_cast<const float4*>(ic_w2 + t * 128);
        double a0 = 0.0, a1 = 0.0, a2 = 0.0, a3 = 0.0;
        #pragma unroll
        for (int k = 0; k < 32; ++k) {
            float4 wv = wr[k];
            double2 h0 = *reinterpret_cast<const double2*>(&smd[D_FB + 4 * k]);
            double2 h1 = *reinterpret_cast<const double2*>(&smd[D_FB + 4 * k + 2]);
            a0 += (double)wv.x * h0.x; a1 += (double)wv.y * h0.y;
            a2 += (double)wv.z * h1.x; a3 += (double)wv.w * h1.y;
        }
        double d;
        smd[D_T3 + t] = lipswish_d((double)ic_b2[t] + (a0 + a2) + (a1 + a3), &d);
    }
    __syncthreads();
    if (t < 64) {
        const float4* wr = reinterpret_cast<const float4*>(ic_w3 + t * 128);
        double a0 = 0.0, a1 = 0.0, a2 = 0.0, a3 = 0.0;
        #pragma unroll
        for (int k = 0; k < 32; ++k) {
            float4 wv = wr[k];
            double2 h0 = *reinterpret_cast<const double2*>(&smd[D_T3 + 4 * k]);
            double2 h1 = *reinterpret_cast<const double2*>(&smd[D_T3 + 4 * k + 2]);
            a0 += (double)wv.x * h0.x; a1 += (double)wv.y * h0.y;
            a2 += (double)wv.z * h1.x; a3 += (double)wv.w * h1.y;
        }
        double y0 = (double)ic_b3[t] + (a0 + a2) + (a1 + a3);
        smd[D_YCUR + t] = y0;
        smd[D_YBUF + t + 2 * (t >> 3)] = y0;
        smd[D_HID + t]  = y0;
        int a = t >> 3, bb = t & 7;
        double cv = 0.0;
        if (a != bb) {
            int i = a < bb ? a : bb;
            int j = a < bb ? bb : a;
            int pidx = 7 * i - (i * (i - 1)) / 2 + (j - i - 1);
            double vv = smd[D_VSIG + 8 + pidx];
            cv = (a > bb) ? vv : -vv;
        }
        smd[D_CMAT + t] = cv;
    }
    __syncthreads();

    // ==== RK4 scan ====
    for (int w = 0; w < 16; ++w) {
        for (int stage = 0; stage < 4; ++stage) {
            // ---- L1 ----
            {
                double acc = 0.0;
                #pragma unroll
                for (int k = 0; k < 8; k += 2) {
                    double2 yv = *reinterpret_cast<const double2*>(&smd[D_YBUF + 10 * p + k]);
                    acc += w1d[k] * yv.x + w1d[k + 1] * yv.y;
                }
                acc = red8(acc);
                if (p == 0) {
                    double d;
                    double h = lipswish_d(acc + b1o, &d);
                    smd[D_H1 + o + 2 * (o >> 4)] = h;
                    smd[D_D1 + o] = d;
                }
            }
            __syncthreads();
            // ---- L2 ----
            {
                double acc = 0.0;
                #pragma unroll
                for (int k = 0; k < 16; k += 2) {
                    double2 hv = *reinterpret_cast<const double2*>(&smd[D_H1 + 18 * p + k]);
                    acc += w2d[k] * hv.x + w2d[k + 1] * hv.y;
                }
                acc = red8(acc);
                if (p == 0) {
                    double d;
                    double h = lipswish_d(acc + b2o, &d);
                    smd[D_H2 + o + 2 * (o >> 4)] = h;
                    smd[D_D2 + o] = d;
                }
            }
            __syncthreads();
            // ---- L3: F = tanh ----
            double F_reg = 0.0;
            {
                double acc = 0.0;
                #pragma unroll
                for (int k = 0; k < 64; k += 2) {
                    double2 hv = *reinterpret_cast<const double2*>(&smd[D_H2 + 72 * q + k + 2 * (k >> 4)]);
                    acc += w3d[k] * hv.x + w3d[k + 1] * hv.y;
                }
                acc = red2(acc);
                if (q == 0) {
                    F_reg = tanh(acc + b3r);
                    smd[D_FB + row3] = F_reg;
                }
            }
            __syncthreads();
            // ---- WM: wm[a][e] = sum_b CMAT[a][b]*F[b][e] ----
            {
                int kw = t & 1, ew = (t >> 1) & 63;
                double s = 0.0;
                #pragma unroll
                for (int i = 0; i < 4; ++i) {
                    int bb = 4 * kw + i;
                    s += smd[D_CMAT + aT * 8 + bb] * smd[D_FB + bb * 64 + ew];
                }
                s = red2(s);
                if (kw == 0) smd[D_WM + aT * 80 + ew + 2 * (ew >> 3)] = s;
            }
            __syncthreads();
            // ---- U1: batched over a ----
            {
                double d1o = smd[D_D1 + o];
                #pragma unroll
                for (int a = 0; a < 8; ++a) {
                    double acc = 0.0;
                    #pragma unroll
                    for (int k = 0; k < 8; k += 2) {
                        double2 mv = *reinterpret_cast<const double2*>(&smd[D_WM + a * 80 + 10 * p + k]);
                        acc += w1d[k] * mv.x + w1d[k + 1] * mv.y;
                    }
                    acc = red8(acc);
                    if (p == 0) smd[D_U1 + a * 144 + o + 2 * (o >> 4)] = acc * d1o;
                }
            }
            __syncthreads();
            // ---- U2: batched over a ----
            {
                double d2o = smd[D_D2 + o];
                #pragma unroll
                for (int a = 0; a < 8; ++a) {
                    double acc = 0.0;
                    #pragma unroll
                    for (int k = 0; k < 16; k += 2) {
                        double2 uv = *reinterpret_cast<const double2*>(&smd[D_U1 + a * 144 + 18 * p + k]);
                        acc += w2d[k] * uv.x + w2d[k + 1] * uv.y;
                    }
                    acc = red8(acc);
                    if (p == 0) smd[D_U2 + a * 144 + o + 2 * (o >> 4)] = acc * d2o;
                }
            }
            __syncthreads();
            // ---- T3 ----
            {
                double acc = 0.0;
                #pragma unroll
                for (int k = 0; k < 64; k += 2) {
                    double2 uv = *reinterpret_cast<const double2*>(&smd[D_U2 + aT * 144 + 72 * q + k + 2 * (k >> 4)]);
                    acc += w3d[k] * uv.x + w3d[k + 1] * uv.y;
                }
                acc = red2(acc);
                if (q == 0) {
                    double va = smd[D_VSIG + w * 36 + aT];
                    smd[D_T3 + row3] = va * F_reg + (1.0 - F_reg * F_reg) * acc;
                }
            }
            __syncthreads();
            // ---- E: combine + RK4 glue (+ next CMAT) ----
            if (t < 64) {
                double g = 0.0;
                #pragma unroll
                for (int a = 0; a < 8; ++a) g += smd[D_T3 + a * 64 + t];
                double y = smd[D_YCUR + t];
                int yp = D_YBUF + t + 2 * (t >> 3);
                if (stage == 0)      { smd[D_KACC + t] = g;        smd[yp] = y + 0.5 * g; }
                else if (stage == 1) { smd[D_KACC + t] += 2.0 * g; smd[yp] = y + 0.5 * g; }
                else if (stage == 2) { smd[D_KACC + t] += 2.0 * g; smd[yp] = y + g; }
                else {
                    double yn = y + (smd[D_KACC + t] + g) * (1.0 / 6.0);
                    smd[D_YCUR + t] = yn;
                    smd[yp] = yn;
                    smd[D_HID + (w + 1) * 64 + t] = yn;
                }
            } else if (t < 128 && stage == 3 && w < 15) {
                int idx = t - 64;
                int a = idx >> 3, bb = idx & 7;
                double cv = 0.0;
                if (a != bb) {
                    int i = a < bb ? a : bb;
                    int j = a < bb ? bb : a;
                    int pidx = 7 * i - (i * (i - 1)) / 2 + (j - i - 1);
                    double vv = smd[D_VSIG + (w + 1) * 36 + 8 + pidx];
                    cv = (a > bb) ? vv : -vv;
                }
                smd[D_CMAT + idx] = cv;
            }
            __syncthreads();
        }
    }

    // ==== readout ====
    for (int idx = t; idx < 544; idx += NT) {
        int s = idx >> 5, oo = idx & 31;
        double acc = (double)ro_b[oo];
        const float* wr = ro_w + oo * 64;
        const double* hr = &smd[D_HID + s * 64];
        #pragma unroll
        for (int d = 0; d < 64; ++d) acc += (double)wr[d] * hr[d];
        out[(size_t)b * 544 + idx] = (float)acc;
    }
}

extern "C" void kernel_launch(void* const* d_in, const int* in_sizes, int n_in,
                              void* d_out, int out_size, void* d_ws, size_t ws_size,
                              hipStream_t stream) {
    const float* x     = (const float*)d_in[0];
    const float* ic_w1 = (const float*)d_in[1];
    const float* ic_b1 = (const float*)d_in[2];
    const float* ic_w2 = (const float*)d_in[3];
    const float* ic_b2 = (const float*)d_in[4];
    const float* ic_w3 = (const float*)d_in[5];
    const float* ic_b3 = (const float*)d_in[6];
    const float* vf_w1 = (const float*)d_in[7];
    const float* vf_b1 = (const float*)d_in[8];
    const float* vf_w2 = (const float*)d_in[9];
    const float* vf_b2 = (const float*)d_in[10];
    const float* vf_w3 = (const float*)d_in[11];
    const float* vf_b3 = (const float*)d_in[12];
    const float* ro_w  = (const float*)d_in[13];
    const float* ro_b  = (const float*)d_in[14];
    float* out = (float*)d_out;

    int B = in_sizes[0] / (257 * 8);
    hipLaunchKernelGGL(ncde_solve, dim3(B), dim3(NT), 0, stream,
                       x, ic_w1, ic_b1, ic_w2, ic_b2, ic_w3, ic_b3,
                       vf_w1, vf_b1, vf_w2, vf_b2, vf_w3, vf_b3, ro_w, ro_b, out);
}